// Round 1
// baseline (80.680 us; speedup 1.0000x reference)
//
#include <hip/hip_runtime.h>

// Reference analysis: softmax over a singleton axis => alpha == 1, so W / kv_proj /
// score are dead code. Output (N=4096, 2D=1024) fp32:
//   out[i, 0:512]    = H[i]  = 2*X[i]                      (i < 64)
//                            = X[i] + sum_{j=i-64}^{i-1} X[j]   (i >= 64)
//   out[i, 512:1024] = X[i]
// Pure memory-bound sliding-window sum.

#define LENS 64
#define RT 8          // rows per thread
#define C4 128        // float4 columns (512 floats / 4)

__global__ __launch_bounds__(256) void winsum_kernel(const float4* __restrict__ X4,
                                                     float4* __restrict__ O4,
                                                     int N) {
    const int c4   = threadIdx.x & (C4 - 1);   // 0..127 -> which float4 of the row
    const int half = threadIdx.x >> 7;         // 0..1   -> row sub-tile
    const int i0   = blockIdx.x * (2 * RT) + half * RT;
    if (i0 >= N) return;

    if (i0 < LENS) {
        // rows < 64: H = 2X, plus copy of X  (RT divides LENS so whole range is < 64)
        for (int k = 0; k < RT; ++k) {
            const int i = i0 + k;
            float4 x = X4[(size_t)i * C4 + c4];
            float4 h = make_float4(2.f * x.x, 2.f * x.y, 2.f * x.z, 2.f * x.w);
            O4[(size_t)i * (2 * C4) + c4]      = h;
            O4[(size_t)i * (2 * C4) + C4 + c4] = x;
        }
        return;
    }

    // Initial window sum over rows [i0-64, i0); stash first RT-1 rows for sliding.
    float4 hist[RT - 1];
    float4 w = make_float4(0.f, 0.f, 0.f, 0.f);
    const float4* p = X4 + (size_t)(i0 - LENS) * C4 + c4;
#pragma unroll
    for (int j = 0; j < LENS; ++j) {
        float4 x = p[(size_t)j * C4];
        if (j < RT - 1) hist[j] = x;
        w.x += x.x; w.y += x.y; w.z += x.z; w.w += x.w;
    }

#pragma unroll
    for (int k = 0; k < RT; ++k) {
        const int i = i0 + k;
        float4 x = X4[(size_t)i * C4 + c4];
        float4 h = make_float4(x.x + w.x, x.y + w.y, x.z + w.z, x.w + w.w);
        O4[(size_t)i * (2 * C4) + c4]      = h;
        O4[(size_t)i * (2 * C4) + C4 + c4] = x;
        if (k < RT - 1) {
            float4 old = hist[k];
            w.x += x.x - old.x;
            w.y += x.y - old.y;
            w.z += x.z - old.z;
            w.w += x.w - old.w;
        }
    }
}

extern "C" void kernel_launch(void* const* d_in, const int* in_sizes, int n_in,
                              void* d_out, int out_size, void* d_ws, size_t ws_size,
                              hipStream_t stream) {
    const float* X = (const float*)d_in[0];   // (N, 512) fp32
    // d_in[1] = W -- dead code in the reference (softmax over singleton axis)
    float* O = (float*)d_out;                 // (N, 1024) fp32

    const int D = 512;
    const int N = in_sizes[0] / D;            // 4096

    const int rows_per_block = 2 * RT;        // 16
    const int grid = (N + rows_per_block - 1) / rows_per_block;  // 256
    winsum_kernel<<<grid, 256, 0, stream>>>((const float4*)X, (float4*)O, N);
}

// Round 2
// 69.299 us; speedup vs baseline: 1.1642x; 1.1642x over previous
//
#include <hip/hip_runtime.h>

// out[i, 0:512]  = 2*X[i]                         (i < 64)
//                = X[i] + sum_{j=i-64}^{i-1} X[j] (i >= 64)
// out[i,512:1024]= X[i]
//
// Two-pass: A) 8-row chunk sums C8[k][c] = sum rows [8k,8k+8); B) window for
// aligned i0 (mult of 8) = sum of 8 C8 chunks, then slide 8 rows.

#define LENS 64
#define RT 8
#define C4 128        // float4 columns per X row (512 floats)

__global__ __launch_bounds__(256) void chunk8_kernel(const float4* __restrict__ X4,
                                                     float4* __restrict__ C8,
                                                     int nChunks) {
    const int t  = blockIdx.x * 256 + threadIdx.x;
    const int c4 = t & (C4 - 1);
    const int k  = t >> 7;
    if (k >= nChunks) return;
    const float4* p = X4 + (size_t)k * 8 * C4 + c4;
    float4 s = make_float4(0.f, 0.f, 0.f, 0.f);
#pragma unroll
    for (int j = 0; j < 8; ++j) {
        float4 x = p[(size_t)j * C4];
        s.x += x.x; s.y += x.y; s.z += x.z; s.w += x.w;
    }
    C8[(size_t)k * C4 + c4] = s;
}

__global__ __launch_bounds__(256) void winsum_kernel(const float4* __restrict__ X4,
                                                     const float4* __restrict__ C8,
                                                     float4* __restrict__ O4,
                                                     int N) {
    const int c4   = threadIdx.x & (C4 - 1);
    const int half = threadIdx.x >> 7;
    const int i0   = blockIdx.x * (2 * RT) + half * RT;
    if (i0 >= N) return;

    if (i0 < LENS) {
#pragma unroll
        for (int k = 0; k < RT; ++k) {
            const int i = i0 + k;
            float4 x = X4[(size_t)i * C4 + c4];
            float4 h = make_float4(2.f * x.x, 2.f * x.y, 2.f * x.z, 2.f * x.w);
            O4[(size_t)i * (2 * C4) + c4]      = h;
            O4[(size_t)i * (2 * C4) + C4 + c4] = x;
        }
        return;
    }

    // initial window = sum of 8 chunk sums covering rows [i0-64, i0)
    const int m = i0 >> 3;   // i0 is a multiple of 8
    float4 w = make_float4(0.f, 0.f, 0.f, 0.f);
#pragma unroll
    for (int q = 0; q < 8; ++q) {
        float4 cs = C8[(size_t)(m - 8 + q) * C4 + c4];
        w.x += cs.x; w.y += cs.y; w.z += cs.z; w.w += cs.w;
    }

    // rows that will leave the window during the slide: [i0-64, i0-58]
    float4 hist[RT - 1];
    const float4* ph = X4 + (size_t)(i0 - LENS) * C4 + c4;
#pragma unroll
    for (int j = 0; j < RT - 1; ++j) hist[j] = ph[(size_t)j * C4];

#pragma unroll
    for (int k = 0; k < RT; ++k) {
        const int i = i0 + k;
        float4 x = X4[(size_t)i * C4 + c4];
        float4 h = make_float4(x.x + w.x, x.y + w.y, x.z + w.z, x.w + w.w);
        O4[(size_t)i * (2 * C4) + c4]      = h;
        O4[(size_t)i * (2 * C4) + C4 + c4] = x;
        if (k < RT - 1) {
            float4 old = hist[k];
            w.x += x.x - old.x;
            w.y += x.y - old.y;
            w.z += x.z - old.z;
            w.w += x.w - old.w;
        }
    }
}

extern "C" void kernel_launch(void* const* d_in, const int* in_sizes, int n_in,
                              void* d_out, int out_size, void* d_ws, size_t ws_size,
                              hipStream_t stream) {
    const float* X = (const float*)d_in[0];   // (N, 512) fp32; d_in[1]=W is dead code
    float* O = (float*)d_out;                 // (N, 1024) fp32
    float* C = (float*)d_ws;                  // (N/8, 512) chunk sums, 1 MB

    const int D = 512;
    const int N = in_sizes[0] / D;            // 4096
    const int nChunks = N / 8;                // 512

    chunk8_kernel<<<(nChunks * C4 + 255) / 256, 256, 0, stream>>>(
        (const float4*)X, (float4*)C, nChunks);

    const int rows_per_block = 2 * RT;        // 16
    winsum_kernel<<<(N + rows_per_block - 1) / rows_per_block, 256, 0, stream>>>(
        (const float4*)X, (const float4*)C, (float4*)O, N);
}